// Round 1
// baseline (981.095 us; speedup 1.0000x reference)
//
#include <hip/hip_runtime.h>

#define PRE_K 1000
#define CAP   2048      // candidate buffer for per-level top-k (>= PRE_K, pow2)
#define NB    1000      // boxes per level after pre-NMS topk
#define NW    16        // 64-bit words covering NB bits (16*64 = 1024)
#define TOT   4000      // concatenated entries per batch
#define TOTP  4096      // padded pow2 for bitonic
#define NLVL  4
#define BATCH 8

__device__ __forceinline__ unsigned f2key(float f) {
    unsigned u = __float_as_uint(f);
    return (u & 0x80000000u) ? ~u : (u | 0x80000000u);   // monotonic ascending
}
__device__ __forceinline__ float key2f(unsigned k) {
    unsigned u = (k & 0x80000000u) ? (k & 0x7FFFFFFFu) : ~k;
    return __uint_as_float(u);
}

// ---------------------------------------------------------------------------
// Kernel 1: per (batch,level) exact top-1000 (stable: score desc, idx asc)
// ---------------------------------------------------------------------------
__global__ __launch_bounds__(1024) void topk_kernel(
    const float* __restrict__ boxes0, const float* __restrict__ scores0,
    const float* __restrict__ boxes1, const float* __restrict__ scores1,
    const float* __restrict__ boxes2, const float* __restrict__ scores2,
    const float* __restrict__ boxes3, const float* __restrict__ scores3,
    float* __restrict__ ws_scores,   // [32][1000]
    float* __restrict__ ws_boxes)    // [32][1000][4]
{
    const int blk = blockIdx.x;          // b*4 + lvl
    const int b   = blk >> 2;
    const int lvl = blk & 3;
    const int sizes[4] = {196608, 49152, 12288, 3072};
    const float* sc; const float* bx;
    switch (lvl) {
        case 0: sc = scores0; bx = boxes0; break;
        case 1: sc = scores1; bx = boxes1; break;
        case 2: sc = scores2; bx = boxes2; break;
        default: sc = scores3; bx = boxes3; break;
    }
    const int n = sizes[lvl];
    sc += (size_t)b * n;
    bx += (size_t)b * n * 4;

    __shared__ unsigned hist[256];
    __shared__ unsigned s_prefix, s_kr, s_cnt;
    __shared__ unsigned long long cand[CAP];

    const int tid = threadIdx.x;

    // ---- 4-pass radix select: key of the 1000th-largest score ----
    unsigned prefix = 0;
    int kr = PRE_K;
    for (int pass = 0; pass < 4; ++pass) {
        if (tid < 256) hist[tid] = 0;
        __syncthreads();
        const int shift = 24 - 8 * pass;
        for (int i = tid; i < n; i += 1024) {
            unsigned u = f2key(sc[i]);
            if (pass == 0 || (u >> (shift + 8)) == prefix)
                atomicAdd(&hist[(u >> shift) & 0xFFu], 1u);
        }
        __syncthreads();
        if (tid == 0) {
            int cum = 0, digit = 0;
            for (int d = 255; d >= 0; --d) {
                int c = (int)hist[d];
                if (cum + c >= kr) { digit = d; break; }
                cum += c;
            }
            s_prefix = (prefix << 8) | (unsigned)digit;
            s_kr = (unsigned)(kr - cum);
        }
        __syncthreads();
        prefix = s_prefix;
        kr = (int)s_kr;
        __syncthreads();
    }
    const unsigned K = prefix;   // full 32-bit key of the 1000th largest

    // ---- collect all keys >= K ----
    if (tid == 0) s_cnt = 0;
    __syncthreads();
    for (int i = tid; i < n; i += 1024) {
        unsigned u = f2key(sc[i]);
        if (u >= K) {
            unsigned p = atomicAdd(&s_cnt, 1u);
            if (p < CAP)
                cand[p] = ((unsigned long long)u << 32) | (unsigned)(~i);
        }
    }
    __syncthreads();
    unsigned cnt = s_cnt; if (cnt > CAP) cnt = CAP;
    for (int i = tid; i < CAP; i += 1024)
        if (i >= (int)cnt) cand[i] = 0ull;
    __syncthreads();

    // ---- bitonic sort CAP composites, descending ----
    for (unsigned kk = 2; kk <= CAP; kk <<= 1) {
        for (unsigned j = kk >> 1; j > 0; j >>= 1) {
            for (unsigned i = tid; i < CAP; i += 1024) {
                unsigned p = i ^ j;
                if (p > i) {
                    unsigned long long a = cand[i], c = cand[p];
                    bool desc = ((i & kk) == 0);
                    if (desc ? (a < c) : (a > c)) { cand[i] = c; cand[p] = a; }
                }
            }
            __syncthreads();
        }
    }

    // ---- emit sorted scores + gathered boxes ----
    for (int r = tid; r < PRE_K; r += 1024) {
        unsigned long long c = cand[r];
        unsigned key = (unsigned)(c >> 32);
        int idx = (int)(~(unsigned)c);
        ws_scores[(size_t)blk * PRE_K + r] = key2f(key);
        float* dst = ws_boxes + ((size_t)blk * PRE_K + r) * 4;
        const float* src = bx + (size_t)idx * 4;
        dst[0] = src[0]; dst[1] = src[1]; dst[2] = src[2]; dst[3] = src[3];
    }
}

// ---------------------------------------------------------------------------
// Kernel 2: per (batch,level) greedy NMS + stable compaction + zero-fill
// ---------------------------------------------------------------------------
__global__ __launch_bounds__(1024) void nms_kernel(
    float* __restrict__ ws_scores,   // [32][1000] in-place
    float* __restrict__ ws_boxes)    // [32][1000][4] in-place
{
    const int blk = blockIdx.x;
    const int tid = threadIdx.x;

    __shared__ float sy1[NB], sx1[NB], sy2[NB], sx2[NB], sarea[NB], ssc[NB];
    __shared__ unsigned long long mask[NB][NW];   // 128 KB: bit j of row i => i suppresses j (j>i)
    __shared__ unsigned long long keepw[NW];
    __shared__ int wprefix[NW];

    float* scp = ws_scores + (size_t)blk * NB;
    float* bxp = ws_boxes  + (size_t)blk * NB * 4;

    for (int i = tid; i < NB; i += 1024) {
        float y1 = bxp[i*4+0], x1 = bxp[i*4+1], y2 = bxp[i*4+2], x2 = bxp[i*4+3];
        sy1[i] = y1; sx1[i] = x1; sy2[i] = y2; sx2[i] = x2;
        sarea[i] = (y2 - y1) * (x2 - x1);
        ssc[i] = scp[i];
    }
    __syncthreads();

    // ---- build suppression bitmask (no atomics: thread <-> (row, word)) ----
    for (int t = tid; t < NB * NW; t += 1024) {
        const int i = t >> 4;          // row
        const int w = t & (NW - 1);    // 64-bit word
        const float y1i = sy1[i], x1i = sx1[i], y2i = sy2[i], x2i = sx2[i], ai = sarea[i];
        unsigned long long m = 0;
        const int jbase = w * 64;
        #pragma unroll 4
        for (int jj = 0; jj < 64; ++jj) {
            const int j = jbase + jj;
            if (j > i && j < NB) {
                float iy1 = fmaxf(y1i, sy1[j]);
                float ix1 = fmaxf(x1i, sx1[j]);
                float iy2 = fminf(y2i, sy2[j]);
                float ix2 = fminf(x2i, sx2[j]);
                float ih = fmaxf(iy2 - iy1, 0.0f);
                float iw = fmaxf(ix2 - ix1, 0.0f);
                float inter = ih * iw;
                float uni = ai + sarea[j] - inter;
                float iou = (uni > 0.0f) ? (inter / uni) : 0.0f;
                if (iou > 0.7f) m |= (1ull << jj);
            }
        }
        mask[i][w] = m;
    }
    __syncthreads();

    // ---- greedy sequential pass: wave 0, keep words lane-resident ----
    if (tid < 64) {
        const int lane = tid;
        unsigned long long kp = 0;
        if (lane < NW) {
            for (int jj = 0; jj < 64; ++jj) {
                int j = lane * 64 + jj;
                if (j < NB && ssc[j] > 0.0f) kp |= (1ull << jj);
            }
        }
        unsigned long long mrow = (lane < NW) ? mask[0][lane] : 0ull;
        for (int i = 0; i < NB; ++i) {
            unsigned long long nxt = (lane < NW && i + 1 < NB) ? mask[i+1][lane] : 0ull;
            unsigned long long ow = __shfl(kp, i >> 6, 64);   // owner word, broadcast
            if ((ow >> (i & 63)) & 1ull) kp &= ~mrow;
            mrow = nxt;
        }
        if (lane < NW) keepw[lane] = kp;
    }
    __syncthreads();
    if (tid == 0) {
        int acc = 0;
        for (int w = 0; w < NW; ++w) { wprefix[w] = acc; acc += __popcll(keepw[w]); }
    }
    __syncthreads();

    // ---- zero-fill then stable scatter of survivors (block barrier orders) ----
    for (int i = tid; i < NB; i += 1024) scp[i] = 0.0f;
    for (int i = tid; i < NB * 4; i += 1024) bxp[i] = 0.0f;
    __syncthreads();
    for (int i = tid; i < NB; i += 1024) {
        const int w = i >> 6;
        const unsigned long long kw = keepw[w];
        if ((kw >> (i & 63)) & 1ull) {
            int rank = wprefix[w] + __popcll(kw & ((1ull << (i & 63)) - 1ull));
            scp[rank] = ssc[i];
            float* dst = bxp + (size_t)rank * 4;
            dst[0] = sy1[i]; dst[1] = sx1[i]; dst[2] = sy2[i]; dst[3] = sx2[i];
        }
    }
}

// ---------------------------------------------------------------------------
// Kernel 3: per-batch final top-1000 over 4000 concatenated entries
// ---------------------------------------------------------------------------
__global__ __launch_bounds__(1024) void final_topk_kernel(
    const float* __restrict__ ws_scores,  // [8][4][1000] == [8][4000]
    const float* __restrict__ ws_boxes,   // [8][4000][4]
    float* __restrict__ out)              // rois (8*1000*4) then scores (8*1000)
{
    const int b = blockIdx.x;
    const int tid = threadIdx.x;
    __shared__ unsigned long long arr[TOTP];

    for (int i = tid; i < TOTP; i += 1024) {
        unsigned long long c = 0ull;
        if (i < TOT) {
            unsigned u = f2key(ws_scores[(size_t)b * TOT + i]);
            c = ((unsigned long long)u << 32) | (unsigned)(~i);
        }
        arr[i] = c;
    }
    __syncthreads();

    for (unsigned kk = 2; kk <= TOTP; kk <<= 1) {
        for (unsigned j = kk >> 1; j > 0; j >>= 1) {
            for (unsigned i = tid; i < TOTP; i += 1024) {
                unsigned p = i ^ j;
                if (p > i) {
                    unsigned long long a = arr[i], c = arr[p];
                    bool desc = ((i & kk) == 0);
                    if (desc ? (a < c) : (a > c)) { arr[i] = c; arr[p] = a; }
                }
            }
            __syncthreads();
        }
    }

    float* out_rois   = out;            // (8,1000,4)
    float* out_scores = out + 32000;    // (8,1000)
    for (int r = tid; r < 1000; r += 1024) {
        unsigned long long c = arr[r];
        int pos = (int)(~(unsigned)c);
        unsigned key = (unsigned)(c >> 32);
        out_scores[(size_t)b * 1000 + r] = key2f(key);
        const float* src = ws_boxes + ((size_t)b * TOT + pos) * 4;
        float* dst = out_rois + ((size_t)b * 1000 + r) * 4;
        dst[0] = src[0]; dst[1] = src[1]; dst[2] = src[2]; dst[3] = src[3];
    }
}

// ---------------------------------------------------------------------------
extern "C" void kernel_launch(void* const* d_in, const int* in_sizes, int n_in,
                              void* d_out, int out_size, void* d_ws, size_t ws_size,
                              hipStream_t stream) {
    // setup_inputs() dict order: boxes_p2, scores_p2, boxes_p3, scores_p3,
    //                            boxes_p4, scores_p4, boxes_p5, scores_p5
    const float* boxes0  = (const float*)d_in[0];
    const float* scores0 = (const float*)d_in[1];
    const float* boxes1  = (const float*)d_in[2];
    const float* scores1 = (const float*)d_in[3];
    const float* boxes2  = (const float*)d_in[4];
    const float* scores2 = (const float*)d_in[5];
    const float* boxes3  = (const float*)d_in[6];
    const float* scores3 = (const float*)d_in[7];
    float* out = (float*)d_out;

    // workspace carve: scores [32*1000] then boxes [32*1000*4]
    float* ws_scores = (float*)d_ws;
    float* ws_boxes  = ws_scores + 32 * PRE_K;

    topk_kernel<<<BATCH * NLVL, 1024, 0, stream>>>(
        boxes0, scores0, boxes1, scores1, boxes2, scores2, boxes3, scores3,
        ws_scores, ws_boxes);
    nms_kernel<<<BATCH * NLVL, 1024, 0, stream>>>(ws_scores, ws_boxes);
    final_topk_kernel<<<BATCH, 1024, 0, stream>>>(ws_scores, ws_boxes, out);
}

// Round 2
// 486.237 us; speedup vs baseline: 2.0177x; 2.0177x over previous
//
#include <hip/hip_runtime.h>

#define PRE_K 1000
#define CAP   2048      // candidate buffer for per-level top-k (>= PRE_K, pow2)
#define NB    1000      // boxes per level after pre-NMS topk
#define NW    16        // 64-bit words covering NB bits (16*64 = 1024)
#define TOT   4000      // concatenated entries per batch
#define TOTP  4096      // padded pow2 for bitonic
#define NLVL  4
#define BATCH 8
#define MB    8         // blocks per (b,lvl) for mask build
#define PFD   20        // prefetch depth in greedy pass (1000 % 20 == 0)

__device__ __forceinline__ unsigned f2key(float f) {
    unsigned u = __float_as_uint(f);
    return (u & 0x80000000u) ? ~u : (u | 0x80000000u);   // monotonic ascending
}
__device__ __forceinline__ float key2f(unsigned k) {
    unsigned u = (k & 0x80000000u) ? (k & 0x7FFFFFFFu) : ~k;
    return __uint_as_float(u);
}

// ---------------------------------------------------------------------------
// Kernel 1: per (batch,level) exact top-1000 (stable: score desc, idx asc)
// ---------------------------------------------------------------------------
__global__ __launch_bounds__(1024) void topk_kernel(
    const float* __restrict__ boxes0, const float* __restrict__ scores0,
    const float* __restrict__ boxes1, const float* __restrict__ scores1,
    const float* __restrict__ boxes2, const float* __restrict__ scores2,
    const float* __restrict__ boxes3, const float* __restrict__ scores3,
    float* __restrict__ ws_scores,   // [32][1000]
    float* __restrict__ ws_boxes)    // [32][1000][4]
{
    const int blk = blockIdx.x;          // b*4 + lvl
    const int b   = blk >> 2;
    const int lvl = blk & 3;
    const int sizes[4] = {196608, 49152, 12288, 3072};
    const float* sc; const float* bx;
    switch (lvl) {
        case 0: sc = scores0; bx = boxes0; break;
        case 1: sc = scores1; bx = boxes1; break;
        case 2: sc = scores2; bx = boxes2; break;
        default: sc = scores3; bx = boxes3; break;
    }
    const int n = sizes[lvl];
    sc += (size_t)b * n;
    bx += (size_t)b * n * 4;

    // 8 bank-staggered histogram replicas (scores ~N(0,1) concentrate in few
    // exponent bins -> heavy same-address LDS atomic serialization otherwise)
    __shared__ unsigned hist[8][257];
    __shared__ unsigned histsum[256];
    __shared__ unsigned s_prefix, s_kr, s_cnt;
    __shared__ unsigned long long cand[CAP];

    const int tid = threadIdx.x;
    const int rep = tid >> 7;            // wave-uniform replica id (2 waves/replica)

    // ---- 4-pass radix select: key of the 1000th-largest score ----
    unsigned prefix = 0;
    int kr = PRE_K;
    for (int pass = 0; pass < 4; ++pass) {
        for (int t = tid; t < 8 * 257; t += 1024) (&hist[0][0])[t] = 0;
        __syncthreads();
        const int shift = 24 - 8 * pass;
        for (int i = tid; i < n; i += 1024) {
            unsigned u = f2key(sc[i]);
            if (pass == 0 || (u >> (shift + 8)) == prefix)
                atomicAdd(&hist[rep][(u >> shift) & 0xFFu], 1u);
        }
        __syncthreads();
        if (tid < 256) {
            unsigned s = 0;
            #pragma unroll
            for (int r = 0; r < 8; ++r) s += hist[r][tid];
            histsum[tid] = s;
        }
        __syncthreads();
        if (tid == 0) {
            int cum = 0, digit = 0;
            for (int d = 255; d >= 0; --d) {
                int c = (int)histsum[d];
                if (cum + c >= kr) { digit = d; break; }
                cum += c;
            }
            s_prefix = (prefix << 8) | (unsigned)digit;
            s_kr = (unsigned)(kr - cum);
        }
        __syncthreads();
        prefix = s_prefix;
        kr = (int)s_kr;
        __syncthreads();
    }
    const unsigned K = prefix;   // full 32-bit key of the 1000th largest

    // ---- collect all keys >= K ----
    if (tid == 0) s_cnt = 0;
    __syncthreads();
    for (int i = tid; i < n; i += 1024) {
        unsigned u = f2key(sc[i]);
        if (u >= K) {
            unsigned p = atomicAdd(&s_cnt, 1u);
            if (p < CAP)
                cand[p] = ((unsigned long long)u << 32) | (unsigned)(~i);
        }
    }
    __syncthreads();
    unsigned cnt = s_cnt; if (cnt > CAP) cnt = CAP;
    for (int i = tid; i < CAP; i += 1024)
        if (i >= (int)cnt) cand[i] = 0ull;
    __syncthreads();

    // ---- bitonic sort CAP composites, descending ----
    for (unsigned kk = 2; kk <= CAP; kk <<= 1) {
        for (unsigned j = kk >> 1; j > 0; j >>= 1) {
            for (unsigned i = tid; i < CAP; i += 1024) {
                unsigned p = i ^ j;
                if (p > i) {
                    unsigned long long a = cand[i], c = cand[p];
                    bool desc = ((i & kk) == 0);
                    if (desc ? (a < c) : (a > c)) { cand[i] = c; cand[p] = a; }
                }
            }
            __syncthreads();
        }
    }

    // ---- emit sorted scores + gathered boxes ----
    for (int r = tid; r < PRE_K; r += 1024) {
        unsigned long long c = cand[r];
        unsigned key = (unsigned)(c >> 32);
        int idx = (int)(~(unsigned)c);
        ws_scores[(size_t)blk * PRE_K + r] = key2f(key);
        float* dst = ws_boxes + ((size_t)blk * PRE_K + r) * 4;
        const float* src = bx + (size_t)idx * 4;
        dst[0] = src[0]; dst[1] = src[1]; dst[2] = src[2]; dst[3] = src[3];
    }
}

// ---------------------------------------------------------------------------
// Kernel 2a: suppression mask build. One wave per row per iteration; word via
// __ballot with j = w*64+lane -> lane-consecutive LDS reads (conflict-free),
// row values broadcast (free). Lower-triangle words skipped, never written.
// ---------------------------------------------------------------------------
__global__ __launch_bounds__(256) void mask_kernel(
    const float* __restrict__ ws_boxes,
    unsigned long long* __restrict__ ws_mask)   // [32][1000][16]
{
    const int blk  = blockIdx.x / MB;    // (b,lvl)
    const int mb   = blockIdx.x % MB;
    const int tid  = threadIdx.x;
    const int lane = tid & 63;
    const int wv   = mb * 4 + (tid >> 6);   // wave id within level, 0..31

    __shared__ float sy1[1024], sx1[1024], sy2[1024], sx2[1024], sarea[1024];

    const float* bxp = ws_boxes + (size_t)blk * NB * 4;
    for (int i = tid; i < 1024; i += 256) {
        float y1 = 0.f, x1 = 0.f, y2 = 0.f, x2 = 0.f;
        if (i < NB) { y1 = bxp[i*4+0]; x1 = bxp[i*4+1]; y2 = bxp[i*4+2]; x2 = bxp[i*4+3]; }
        sy1[i] = y1; sx1[i] = x1; sy2[i] = y2; sx2[i] = x2;
        sarea[i] = (y2 - y1) * (x2 - x1);
    }
    __syncthreads();

    unsigned long long* maskp = ws_mask + (size_t)blk * NB * NW;
    for (int i = wv; i < NB; i += 32) {
        const float y1i = sy1[i], x1i = sx1[i], y2i = sy2[i], x2i = sx2[i], ai = sarea[i];
        for (int w = i >> 6; w < NW; ++w) {
            const int j = w * 64 + lane;
            float iy1 = fmaxf(y1i, sy1[j]);
            float ix1 = fmaxf(x1i, sx1[j]);
            float iy2 = fminf(y2i, sy2[j]);
            float ix2 = fminf(x2i, sx2[j]);
            float ih = fmaxf(iy2 - iy1, 0.0f);
            float iw = fmaxf(ix2 - ix1, 0.0f);
            float inter = ih * iw;
            float uni = ai + sarea[j] - inter;
            // exact IEEE division to match the numpy reference bit-for-bit
            bool pred = (j > i) && (j < NB) && (uni > 0.0f) && (inter / uni > 0.7f);
            unsigned long long m = __ballot(pred);
            if (lane == 0) maskp[i * NW + w] = m;
        }
    }
}

// ---------------------------------------------------------------------------
// Kernel 2b: greedy sequential NMS pass + stable compaction + zero-fill.
// Wave 0 holds keep bits lane-resident; mask rows streamed from L2 with a
// PFD-deep unrolled register prefetch ring (static indexing -> no scratch).
// ---------------------------------------------------------------------------
__global__ __launch_bounds__(256) void greedy_kernel(
    float* __restrict__ ws_scores,   // [32][1000] in-place
    float* __restrict__ ws_boxes,    // [32][1000][4] in-place
    const unsigned long long* __restrict__ ws_mask)
{
    const int blk = blockIdx.x;
    const int tid = threadIdx.x;

    __shared__ float sy1[NB], sx1[NB], sy2[NB], sx2[NB], ssc[NB];
    __shared__ unsigned long long keepw[NW];
    __shared__ int wprefix[NW];

    float* scp = ws_scores + (size_t)blk * NB;
    float* bxp = ws_boxes  + (size_t)blk * NB * 4;

    for (int i = tid; i < NB; i += 256) {
        sy1[i] = bxp[i*4+0]; sx1[i] = bxp[i*4+1];
        sy2[i] = bxp[i*4+2]; sx2[i] = bxp[i*4+3];
        ssc[i] = scp[i];
    }
    __syncthreads();

    if (tid < 64) {
        const int l = tid;
        unsigned long long kp = 0ull;
        if (l < NW) {
            for (int jj = 0; jj < 64; ++jj) {
                int j = l * 64 + jj;
                if (j < NB && ssc[j] > 0.0f) kp |= (1ull << jj);
            }
        }
        const unsigned long long* mrows = ws_mask + (size_t)blk * NB * NW;
        unsigned long long buf[PFD];
        #pragma unroll
        for (int d = 0; d < PFD; ++d)
            buf[d] = (l < NW) ? mrows[d * NW + l] : 0ull;
        for (int ib = 0; ib < NB; ib += PFD) {
            #pragma unroll
            for (int d = 0; d < PFD; ++d) {
                const int i = ib + d;
                // words below the diagonal were never written -> mask them off
                unsigned long long mrow = (l >= (i >> 6)) ? buf[d] : 0ull;
                const int nx = i + PFD;
                buf[d] = (l < NW && nx < NB) ? mrows[nx * NW + l] : 0ull;
                unsigned long long ow = __shfl(kp, i >> 6, 64);
                if ((ow >> (i & 63)) & 1ull) kp &= ~mrow;
            }
        }
        if (l < NW) keepw[l] = kp;
    }
    __syncthreads();
    if (tid == 0) {
        int acc = 0;
        for (int w = 0; w < NW; ++w) { wprefix[w] = acc; acc += __popcll(keepw[w]); }
    }
    __syncthreads();

    for (int i = tid; i < NB; i += 256) scp[i] = 0.0f;
    for (int i = tid; i < NB * 4; i += 256) bxp[i] = 0.0f;
    __syncthreads();
    for (int i = tid; i < NB; i += 256) {
        const int w = i >> 6;
        const unsigned long long kw = keepw[w];
        if ((kw >> (i & 63)) & 1ull) {
            int rank = wprefix[w] + __popcll(kw & ((1ull << (i & 63)) - 1ull));
            scp[rank] = ssc[i];
            float* dst = bxp + (size_t)rank * 4;
            dst[0] = sy1[i]; dst[1] = sx1[i]; dst[2] = sy2[i]; dst[3] = sx2[i];
        }
    }
}

// ---------------------------------------------------------------------------
// Kernel 3: per-batch final top-1000 over 4000 concatenated entries
// ---------------------------------------------------------------------------
__global__ __launch_bounds__(1024) void final_topk_kernel(
    const float* __restrict__ ws_scores,  // [8][4][1000] == [8][4000]
    const float* __restrict__ ws_boxes,   // [8][4000][4]
    float* __restrict__ out)              // rois (8*1000*4) then scores (8*1000)
{
    const int b = blockIdx.x;
    const int tid = threadIdx.x;
    __shared__ unsigned long long arr[TOTP];

    for (int i = tid; i < TOTP; i += 1024) {
        unsigned long long c = 0ull;
        if (i < TOT) {
            unsigned u = f2key(ws_scores[(size_t)b * TOT + i]);
            c = ((unsigned long long)u << 32) | (unsigned)(~i);
        }
        arr[i] = c;
    }
    __syncthreads();

    for (unsigned kk = 2; kk <= TOTP; kk <<= 1) {
        for (unsigned j = kk >> 1; j > 0; j >>= 1) {
            for (unsigned i = tid; i < TOTP; i += 1024) {
                unsigned p = i ^ j;
                if (p > i) {
                    unsigned long long a = arr[i], c = arr[p];
                    bool desc = ((i & kk) == 0);
                    if (desc ? (a < c) : (a > c)) { arr[i] = c; arr[p] = a; }
                }
            }
            __syncthreads();
        }
    }

    float* out_rois   = out;            // (8,1000,4)
    float* out_scores = out + 32000;    // (8,1000)
    for (int r = tid; r < 1000; r += 1024) {
        unsigned long long c = arr[r];
        int pos = (int)(~(unsigned)c);
        unsigned key = (unsigned)(c >> 32);
        out_scores[(size_t)b * 1000 + r] = key2f(key);
        const float* src = ws_boxes + ((size_t)b * TOT + pos) * 4;
        float* dst = out_rois + ((size_t)b * 1000 + r) * 4;
        dst[0] = src[0]; dst[1] = src[1]; dst[2] = src[2]; dst[3] = src[3];
    }
}

// ---------------------------------------------------------------------------
extern "C" void kernel_launch(void* const* d_in, const int* in_sizes, int n_in,
                              void* d_out, int out_size, void* d_ws, size_t ws_size,
                              hipStream_t stream) {
    // setup_inputs() dict order: boxes_p2, scores_p2, boxes_p3, scores_p3,
    //                            boxes_p4, scores_p4, boxes_p5, scores_p5
    const float* boxes0  = (const float*)d_in[0];
    const float* scores0 = (const float*)d_in[1];
    const float* boxes1  = (const float*)d_in[2];
    const float* scores1 = (const float*)d_in[3];
    const float* boxes2  = (const float*)d_in[4];
    const float* scores2 = (const float*)d_in[5];
    const float* boxes3  = (const float*)d_in[6];
    const float* scores3 = (const float*)d_in[7];
    float* out = (float*)d_out;

    // workspace carve: scores [32*1000] | boxes [32*1000*4] | mask [32*1000*16 u64]
    float* ws_scores = (float*)d_ws;
    float* ws_boxes  = ws_scores + 32 * PRE_K;                 // +128000 B
    unsigned long long* ws_mask =
        (unsigned long long*)(ws_boxes + 32 * PRE_K * 4);      // at 640000 B, 8B-aligned

    topk_kernel<<<BATCH * NLVL, 1024, 0, stream>>>(
        boxes0, scores0, boxes1, scores1, boxes2, scores2, boxes3, scores3,
        ws_scores, ws_boxes);
    mask_kernel<<<BATCH * NLVL * MB, 256, 0, stream>>>(ws_boxes, ws_mask);
    greedy_kernel<<<BATCH * NLVL, 256, 0, stream>>>(ws_scores, ws_boxes, ws_mask);
    final_topk_kernel<<<BATCH, 1024, 0, stream>>>(ws_scores, ws_boxes, out);
}

// Round 3
// 351.538 us; speedup vs baseline: 2.7909x; 1.3832x over previous
//
#include <hip/hip_runtime.h>

#define PRE_K 1000
#define CAP   2048      // candidate buffer per level (>= PRE_K + max bin, pow2)
#define NBIN  8192      // 13-bit key-prefix histogram bins
#define NB    1000      // boxes per level after pre-NMS topk
#define NW    16        // 64-bit words covering NB bits (16*64 = 1024)
#define TOT   4000      // concatenated entries per batch
#define TOTP  4096      // padded pow2 for bitonic
#define NLVL  4
#define BATCH 8
#define MB    8         // blocks per (b,lvl) for mask build
#define HB    8         // blocks per (b,lvl) for hist/collect
#define PFD   20        // prefetch depth in greedy pass (1000 % 20 == 0)

__device__ __forceinline__ unsigned f2key(float f) {
    unsigned u = __float_as_uint(f);
    return (u & 0x80000000u) ? ~u : (u | 0x80000000u);   // monotonic ascending
}
__device__ __forceinline__ float key2f(unsigned k) {
    unsigned u = (k & 0x80000000u) ? (k & 0x7FFFFFFFu) : ~k;
    return __uint_as_float(u);
}
__device__ __forceinline__ const float* lvl_scores(
    const float* s0, const float* s1, const float* s2, const float* s3, int lvl) {
    switch (lvl) { case 0: return s0; case 1: return s1; case 2: return s2; default: return s3; }
}
__device__ __forceinline__ const float* lvl_boxes(
    const float* b0, const float* b1, const float* b2, const float* b3, int lvl) {
    switch (lvl) { case 0: return b0; case 1: return b1; case 2: return b2; default: return b3; }
}
__device__ __forceinline__ int lvl_n(int lvl) {
    const int sizes[4] = {196608, 49152, 12288, 3072};
    return sizes[lvl];
}

// ---------------------------------------------------------------------------
// T0: zero global histograms
// ---------------------------------------------------------------------------
__global__ __launch_bounds__(512) void init_kernel(unsigned* __restrict__ ghist) {
    const int stride = gridDim.x * 512;
    for (int i = blockIdx.x * 512 + threadIdx.x; i < 32 * NBIN; i += stride)
        ghist[i] = 0u;
}

// ---------------------------------------------------------------------------
// T1: per-(b,lvl) 13-bit-prefix histogram (LDS partial, flush nonzero bins)
// ---------------------------------------------------------------------------
__global__ __launch_bounds__(512) void hist_kernel(
    const float* __restrict__ scores0, const float* __restrict__ scores1,
    const float* __restrict__ scores2, const float* __restrict__ scores3,
    unsigned* __restrict__ ghist)      // [32][NBIN]
{
    const int blk = blockIdx.x / HB;   // b*4 + lvl
    const int hb  = blockIdx.x % HB;
    const int b   = blk >> 2;
    const int lvl = blk & 3;
    const int n   = lvl_n(lvl);
    const float* sc = lvl_scores(scores0, scores1, scores2, scores3, lvl) + (size_t)b * n;

    __shared__ unsigned lhist[NBIN];
    const int tid = threadIdx.x;
    for (int i = tid; i < NBIN; i += 512) lhist[i] = 0u;
    __syncthreads();

    for (int i = hb * 512 + tid; i < n; i += HB * 512)
        atomicAdd(&lhist[f2key(sc[i]) >> 19], 1u);
    __syncthreads();

    unsigned* gh = ghist + (size_t)blk * NBIN;
    for (int i = tid; i < NBIN; i += 512) {
        unsigned v = lhist[i];
        if (v) atomicAdd(&gh[i], v);
    }
}

// ---------------------------------------------------------------------------
// T2: per-(b,lvl) threshold-bin selection (top-PRE_K boundary); zero counters
// ---------------------------------------------------------------------------
__global__ __launch_bounds__(256) void select_kernel(
    const unsigned* __restrict__ ghist,   // [32][NBIN]
    unsigned* __restrict__ thresh,        // [32]
    unsigned* __restrict__ counters)      // [32]
{
    const int blk = blockIdx.x;
    const int tid = threadIdx.x;
    const unsigned* gh = ghist + (size_t)blk * NBIN;

    __shared__ unsigned csum[256];
    __shared__ int s_chunk;
    __shared__ unsigned s_before;

    // chunk sums: thread t covers bins [t*32, t*32+32)
    unsigned s = 0;
    #pragma unroll 8
    for (int k = 0; k < 32; ++k) s += gh[tid * 32 + k];
    csum[tid] = s;
    __syncthreads();

    // suffix over chunks ABOVE tid (LDS broadcast reads)
    unsigned suf = 0;
    for (int c = tid + 1; c < 256; ++c) suf += csum[c];
    // unique chunk where the top-PRE_K boundary falls
    if (suf < PRE_K && suf + csum[tid] >= PRE_K) { s_chunk = tid; s_before = suf; }
    __syncthreads();

    if (tid == 0) {
        int C = s_chunk;
        unsigned acc = s_before;
        int T = C * 32;
        for (int bin = C * 32 + 31; bin >= C * 32; --bin) {
            acc += gh[bin];
            if (acc >= PRE_K) { T = bin; break; }
        }
        thresh[blk]   = (unsigned)T;
        counters[blk] = 0u;       // zero collect counter for this level
    }
}

// ---------------------------------------------------------------------------
// T3: collect all candidates with key-bin >= threshold (wave-aggregated append)
// ---------------------------------------------------------------------------
__global__ __launch_bounds__(512) void collect_kernel(
    const float* __restrict__ scores0, const float* __restrict__ scores1,
    const float* __restrict__ scores2, const float* __restrict__ scores3,
    const unsigned* __restrict__ thresh,
    unsigned* __restrict__ counters,
    unsigned long long* __restrict__ cand)   // [32][CAP]
{
    const int blk = blockIdx.x / HB;
    const int hb  = blockIdx.x % HB;
    const int b   = blk >> 2;
    const int lvl = blk & 3;
    const int n   = lvl_n(lvl);
    const float* sc = lvl_scores(scores0, scores1, scores2, scores3, lvl) + (size_t)b * n;
    const unsigned T = thresh[blk];
    unsigned* cnt_ptr = counters + blk;
    unsigned long long* candp = cand + (size_t)blk * CAP;

    const int tid  = threadIdx.x;
    const int lane = tid & 63;

    for (int i = hb * 512 + tid; i < n; i += HB * 512) {
        unsigned key = f2key(sc[i]);
        bool pred = (key >> 19) >= T;
        unsigned long long act = __ballot(pred);
        if (act) {
            int leader = __ffsll((long long)act) - 1;
            unsigned base = 0;
            if (lane == leader) base = atomicAdd(cnt_ptr, (unsigned)__popcll(act));
            base = __shfl(base, leader, 64);
            if (pred) {
                unsigned pos = base + (unsigned)__popcll(act & ((1ull << lane) - 1ull));
                if (pos < CAP)
                    candp[pos] = ((unsigned long long)key << 32) | (unsigned)(~i);
            }
        }
    }
}

// ---------------------------------------------------------------------------
// T4: per-(b,lvl) bitonic sort of candidates, emit top-1000 scores + boxes
// ---------------------------------------------------------------------------
__global__ __launch_bounds__(1024) void sortemit_kernel(
    const float* __restrict__ boxes0, const float* __restrict__ boxes1,
    const float* __restrict__ boxes2, const float* __restrict__ boxes3,
    const unsigned* __restrict__ counters,
    const unsigned long long* __restrict__ cand,
    float* __restrict__ ws_scores,   // [32][1000]
    float* __restrict__ ws_boxes)    // [32][1000][4]
{
    const int blk = blockIdx.x;
    const int b   = blk >> 2;
    const int lvl = blk & 3;
    const int n   = lvl_n(lvl);
    const float* bx = lvl_boxes(boxes0, boxes1, boxes2, boxes3, lvl) + (size_t)b * n * 4;
    const unsigned long long* candp = cand + (size_t)blk * CAP;

    __shared__ unsigned long long arr[CAP];
    const int tid = threadIdx.x;
    unsigned cnt = counters[blk]; if (cnt > CAP) cnt = CAP;

    for (int i = tid; i < CAP; i += 1024)
        arr[i] = (i < (int)cnt) ? candp[i] : 0ull;
    __syncthreads();

    for (unsigned kk = 2; kk <= CAP; kk <<= 1) {
        for (unsigned j = kk >> 1; j > 0; j >>= 1) {
            for (unsigned i = tid; i < CAP; i += 1024) {
                unsigned p = i ^ j;
                if (p > i) {
                    unsigned long long a = arr[i], c = arr[p];
                    bool desc = ((i & kk) == 0);
                    if (desc ? (a < c) : (a > c)) { arr[i] = c; arr[p] = a; }
                }
            }
            __syncthreads();
        }
    }

    for (int r = tid; r < PRE_K; r += 1024) {
        unsigned long long c = arr[r];
        unsigned key = (unsigned)(c >> 32);
        int idx = (int)(~(unsigned)c);
        ws_scores[(size_t)blk * PRE_K + r] = key2f(key);
        float* dst = ws_boxes + ((size_t)blk * PRE_K + r) * 4;
        const float* src = bx + (size_t)idx * 4;
        dst[0] = src[0]; dst[1] = src[1]; dst[2] = src[2]; dst[3] = src[3];
    }
}

// ---------------------------------------------------------------------------
// Kernel 2a: suppression mask build. One wave per row per iteration; word via
// __ballot with j = w*64+lane -> lane-consecutive LDS reads (conflict-free),
// row values broadcast (free). Lower-triangle words skipped, never written.
// ---------------------------------------------------------------------------
__global__ __launch_bounds__(256) void mask_kernel(
    const float* __restrict__ ws_boxes,
    unsigned long long* __restrict__ ws_mask)   // [32][1000][16]
{
    const int blk  = blockIdx.x / MB;    // (b,lvl)
    const int mb   = blockIdx.x % MB;
    const int tid  = threadIdx.x;
    const int lane = tid & 63;
    const int wv   = mb * 4 + (tid >> 6);   // wave id within level, 0..31

    __shared__ float sy1[1024], sx1[1024], sy2[1024], sx2[1024], sarea[1024];

    const float* bxp = ws_boxes + (size_t)blk * NB * 4;
    for (int i = tid; i < 1024; i += 256) {
        float y1 = 0.f, x1 = 0.f, y2 = 0.f, x2 = 0.f;
        if (i < NB) { y1 = bxp[i*4+0]; x1 = bxp[i*4+1]; y2 = bxp[i*4+2]; x2 = bxp[i*4+3]; }
        sy1[i] = y1; sx1[i] = x1; sy2[i] = y2; sx2[i] = x2;
        sarea[i] = (y2 - y1) * (x2 - x1);
    }
    __syncthreads();

    unsigned long long* maskp = ws_mask + (size_t)blk * NB * NW;
    for (int i = wv; i < NB; i += 32) {
        const float y1i = sy1[i], x1i = sx1[i], y2i = sy2[i], x2i = sx2[i], ai = sarea[i];
        for (int w = i >> 6; w < NW; ++w) {
            const int j = w * 64 + lane;
            float iy1 = fmaxf(y1i, sy1[j]);
            float ix1 = fmaxf(x1i, sx1[j]);
            float iy2 = fminf(y2i, sy2[j]);
            float ix2 = fminf(x2i, sx2[j]);
            float ih = fmaxf(iy2 - iy1, 0.0f);
            float iw = fmaxf(ix2 - ix1, 0.0f);
            float inter = ih * iw;
            float uni = ai + sarea[j] - inter;
            // exact IEEE division to match the numpy reference bit-for-bit
            bool pred = (j > i) && (j < NB) && (uni > 0.0f) && (inter / uni > 0.7f);
            unsigned long long m = __ballot(pred);
            if (lane == 0) maskp[i * NW + w] = m;
        }
    }
}

// ---------------------------------------------------------------------------
// Kernel 2b: greedy sequential NMS pass + stable compaction + zero-fill.
// Wave 0 holds keep bits lane-resident; mask rows streamed from L2 with a
// PFD-deep unrolled register prefetch ring (static indexing -> no scratch).
// ---------------------------------------------------------------------------
__global__ __launch_bounds__(256) void greedy_kernel(
    float* __restrict__ ws_scores,   // [32][1000] in-place
    float* __restrict__ ws_boxes,    // [32][1000][4] in-place
    const unsigned long long* __restrict__ ws_mask)
{
    const int blk = blockIdx.x;
    const int tid = threadIdx.x;

    __shared__ float sy1[NB], sx1[NB], sy2[NB], sx2[NB], ssc[NB];
    __shared__ unsigned long long keepw[NW];
    __shared__ int wprefix[NW];

    float* scp = ws_scores + (size_t)blk * NB;
    float* bxp = ws_boxes  + (size_t)blk * NB * 4;

    for (int i = tid; i < NB; i += 256) {
        sy1[i] = bxp[i*4+0]; sx1[i] = bxp[i*4+1];
        sy2[i] = bxp[i*4+2]; sx2[i] = bxp[i*4+3];
        ssc[i] = scp[i];
    }
    __syncthreads();

    if (tid < 64) {
        const int l = tid;
        unsigned long long kp = 0ull;
        if (l < NW) {
            for (int jj = 0; jj < 64; ++jj) {
                int j = l * 64 + jj;
                if (j < NB && ssc[j] > 0.0f) kp |= (1ull << jj);
            }
        }
        const unsigned long long* mrows = ws_mask + (size_t)blk * NB * NW;
        unsigned long long buf[PFD];
        #pragma unroll
        for (int d = 0; d < PFD; ++d)
            buf[d] = (l < NW) ? mrows[d * NW + l] : 0ull;
        for (int ib = 0; ib < NB; ib += PFD) {
            #pragma unroll
            for (int d = 0; d < PFD; ++d) {
                const int i = ib + d;
                // words below the diagonal were never written -> mask them off
                unsigned long long mrow = (l >= (i >> 6)) ? buf[d] : 0ull;
                const int nx = i + PFD;
                buf[d] = (l < NW && nx < NB) ? mrows[nx * NW + l] : 0ull;
                unsigned long long ow = __shfl(kp, i >> 6, 64);
                if ((ow >> (i & 63)) & 1ull) kp &= ~mrow;
            }
        }
        if (l < NW) keepw[l] = kp;
    }
    __syncthreads();
    if (tid == 0) {
        int acc = 0;
        for (int w = 0; w < NW; ++w) { wprefix[w] = acc; acc += __popcll(keepw[w]); }
    }
    __syncthreads();

    for (int i = tid; i < NB; i += 256) scp[i] = 0.0f;
    for (int i = tid; i < NB * 4; i += 256) bxp[i] = 0.0f;
    __syncthreads();
    for (int i = tid; i < NB; i += 256) {
        const int w = i >> 6;
        const unsigned long long kw = keepw[w];
        if ((kw >> (i & 63)) & 1ull) {
            int rank = wprefix[w] + __popcll(kw & ((1ull << (i & 63)) - 1ull));
            scp[rank] = ssc[i];
            float* dst = bxp + (size_t)rank * 4;
            dst[0] = sy1[i]; dst[1] = sx1[i]; dst[2] = sy2[i]; dst[3] = sx2[i];
        }
    }
}

// ---------------------------------------------------------------------------
// Kernel 3: per-batch final top-1000 over 4000 concatenated entries
// ---------------------------------------------------------------------------
__global__ __launch_bounds__(1024) void final_topk_kernel(
    const float* __restrict__ ws_scores,  // [8][4][1000] == [8][4000]
    const float* __restrict__ ws_boxes,   // [8][4000][4]
    float* __restrict__ out)              // rois (8*1000*4) then scores (8*1000)
{
    const int b = blockIdx.x;
    const int tid = threadIdx.x;
    __shared__ unsigned long long arr[TOTP];

    for (int i = tid; i < TOTP; i += 1024) {
        unsigned long long c = 0ull;
        if (i < TOT) {
            unsigned u = f2key(ws_scores[(size_t)b * TOT + i]);
            c = ((unsigned long long)u << 32) | (unsigned)(~i);
        }
        arr[i] = c;
    }
    __syncthreads();

    for (unsigned kk = 2; kk <= TOTP; kk <<= 1) {
        for (unsigned j = kk >> 1; j > 0; j >>= 1) {
            for (unsigned i = tid; i < TOTP; i += 1024) {
                unsigned p = i ^ j;
                if (p > i) {
                    unsigned long long a = arr[i], c = arr[p];
                    bool desc = ((i & kk) == 0);
                    if (desc ? (a < c) : (a > c)) { arr[i] = c; arr[p] = a; }
                }
            }
            __syncthreads();
        }
    }

    float* out_rois   = out;            // (8,1000,4)
    float* out_scores = out + 32000;    // (8,1000)
    for (int r = tid; r < 1000; r += 1024) {
        unsigned long long c = arr[r];
        int pos = (int)(~(unsigned)c);
        unsigned key = (unsigned)(c >> 32);
        out_scores[(size_t)b * 1000 + r] = key2f(key);
        const float* src = ws_boxes + ((size_t)b * TOT + pos) * 4;
        float* dst = out_rois + ((size_t)b * 1000 + r) * 4;
        dst[0] = src[0]; dst[1] = src[1]; dst[2] = src[2]; dst[3] = src[3];
    }
}

// ---------------------------------------------------------------------------
extern "C" void kernel_launch(void* const* d_in, const int* in_sizes, int n_in,
                              void* d_out, int out_size, void* d_ws, size_t ws_size,
                              hipStream_t stream) {
    // setup_inputs() dict order: boxes_p2, scores_p2, boxes_p3, scores_p3,
    //                            boxes_p4, scores_p4, boxes_p5, scores_p5
    const float* boxes0  = (const float*)d_in[0];
    const float* scores0 = (const float*)d_in[1];
    const float* boxes1  = (const float*)d_in[2];
    const float* scores1 = (const float*)d_in[3];
    const float* boxes2  = (const float*)d_in[4];
    const float* scores2 = (const float*)d_in[5];
    const float* boxes3  = (const float*)d_in[6];
    const float* scores3 = (const float*)d_in[7];
    float* out = (float*)d_out;

    // ws carve: scores [32*1000] | boxes [32*1000*4] | mask [32*1000*16 u64]
    // The topk pipeline's hist/cand/counters/thresh OVERLAY the mask region
    // (all consumed before mask_kernel writes it).
    char* base = (char*)d_ws;
    float* ws_scores = (float*)base;                               // 128000 B
    float* ws_boxes  = (float*)(base + 128000);                    // 512000 B
    unsigned long long* ws_mask = (unsigned long long*)(base + 640000);  // 4096000 B
    // overlay inside mask region:
    unsigned long long* cand = (unsigned long long*)(base + 640000);     // 524288 B
    unsigned* ghist    = (unsigned*)(base + 1164288);              // 1048576 B
    unsigned* counters = (unsigned*)(base + 2212864);              // 128 B
    unsigned* thresh   = (unsigned*)(base + 2212992);              // 128 B

    init_kernel<<<128, 512, 0, stream>>>(ghist);
    hist_kernel<<<BATCH * NLVL * HB, 512, 0, stream>>>(
        scores0, scores1, scores2, scores3, ghist);
    select_kernel<<<BATCH * NLVL, 256, 0, stream>>>(ghist, thresh, counters);
    collect_kernel<<<BATCH * NLVL * HB, 512, 0, stream>>>(
        scores0, scores1, scores2, scores3, thresh, counters, cand);
    sortemit_kernel<<<BATCH * NLVL, 1024, 0, stream>>>(
        boxes0, boxes1, boxes2, boxes3, counters, cand, ws_scores, ws_boxes);
    mask_kernel<<<BATCH * NLVL * MB, 256, 0, stream>>>(ws_boxes, ws_mask);
    greedy_kernel<<<BATCH * NLVL, 256, 0, stream>>>(ws_scores, ws_boxes, ws_mask);
    final_topk_kernel<<<BATCH, 1024, 0, stream>>>(ws_scores, ws_boxes, out);
}